// Round 7
// baseline (46.274 us; speedup 1.0000x reference)
//
#include <hip/hip_runtime.h>

// Fused FAC (per-pixel 3x3 convolution with residual):
// out[n,c,h,w] = feat[n,c,h,w] + sum_{i,j} feat_pad[n,c,h+i,w+j] * att[n,i*3+j,h,w]
// feature: [8,64,256,256] f32, attention: [8,9,256,256] f32, out: [8,64,256,256] f32.
//
// Round-7: round-6 (45.7us, 4.57 TB/s) still spent ~45% of CU cycles on the
// LDS pipe (gll write + ds_read + shuffles) -- LDS was only a workaround for
// the regalloc sinking plain loads (rounds 2-3). This round: stage straight
// into VGPRs with inline-asm global_load_dwordx4 (volatile asm = unsinkable,
// unrematerializable), same counted-vmcnt schedule, zero LDS in the data path.
// sched_barrier(0) after each waitcnt (rule #18) so FMAs can't hoist above it.

constexpr int N_ = 8, C_ = 64, H_ = 256, W_ = 256;
constexpr int ROWS = 4;                 // output rows per block (1 per wave)
constexpr int CG = 2;                   // channel groups (blocks per pixel tile)
constexpr int CPG = C_ / CG;            // 32 channels per block
constexpr int HB = H_ / ROWS;           // 64 row tiles
constexpr int NWG = N_ * HB * CG;       // 1024 blocks
constexpr int NXCD = 8;

using f32x4 = __attribute__((ext_vector_type(4))) float;

__global__ __launch_bounds__(256, 4) void fac_kernel(
    const float* __restrict__ feat, const float* __restrict__ att,
    float* __restrict__ out) {
  // XCD-aware bijective swizzle (NWG % 8 == 0).
  int bid = blockIdx.x;
  int lg = (bid % NXCD) * (NWG / NXCD) + bid / NXCD;
  int cg = lg % CG;
  int hb = (lg / CG) % HB;
  int n  = lg / (CG * HB);

  int tx = threadIdx.x & 63;   // lane: w4 = tx*4 (wave spans full W row)
  int rt = threadIdx.x >> 6;   // wave id = output row within tile
  int h  = hb * ROWS + rt;
  int w4 = tx << 2;

  const size_t plane = (size_t)H_ * W_;

  // Attention taps in registers, reused across all CPG channels (36 VGPRs).
  const float* attp = att + ((size_t)n * 9 * H_ + h) * (size_t)W_ + w4;
  float4 a[9];
#pragma unroll
  for (int t = 0; t < 9; ++t) a[t] = *(const float4*)(attp + (size_t)t * plane);
#pragma unroll
  for (int t = 0; t < 9; ++t)                // keep-alive; also drains att
    asm volatile("" : "+v"(a[t].x), "+v"(a[t].y), "+v"(a[t].z), "+v"(a[t].w));
  // loads before the loop so our vmcnt counts are exact.

  const float* fbase = feat + ((size_t)n * C_ + (size_t)cg * CPG) * plane;
  float* obase = out + ((size_t)n * C_ + (size_t)cg * CPG) * plane
                     + (size_t)h * W_ + w4;

  // Clamped source rows (uniform load count keeps vmcnt exact; clamped rows
  // are zeroed post-load via wave-uniform cndmask).
  const int g0 = max(h - 1, 0), g2 = min(h + 1, H_ - 1);
  const float* s0 = fbase + (size_t)g0 * W_ + w4;
  const float* s1 = fbase + (size_t)h  * W_ + w4;
  const float* s2 = fbase + (size_t)g2 * W_ + w4;

  const bool hasUp = (h > 0);        // wave-uniform
  const bool hasDn = (h < H_ - 1);   // wave-uniform

  // 3-deep register ring: q[slot][row]; all indices static after full unroll.
  f32x4 q[3][3];

  auto LOAD = [&](int ch, int slot) {
    const float* a0 = s0 + (size_t)ch * plane;
    const float* a1 = s1 + (size_t)ch * plane;
    const float* a2 = s2 + (size_t)ch * plane;
    asm volatile("global_load_dwordx4 %0, %1, off"
                 : "=v"(q[slot][0]) : "v"(a0) : "memory");
    asm volatile("global_load_dwordx4 %0, %1, off"
                 : "=v"(q[slot][1]) : "v"(a1) : "memory");
    asm volatile("global_load_dwordx4 %0, %1, off"
                 : "=v"(q[slot][2]) : "v"(a2) : "memory");
  };

  LOAD(0, 0);
  LOAD(1, 1);

#pragma unroll
  for (int c = 0; c < CPG; ++c) {
    const int s  = c % 3;
    const int s2i = (c + 2) % 3;

    // Counted per-wave waits (no barriers; everything is wave-private).
    // FIFO at this point (steady): L(c):3, st(c-2):1, L(c+1):3, st(c-1):1
    //  -> drain L(c) = leave 5. Prologue/epilogue adjust.
    if (c == 0)
      asm volatile("s_waitcnt vmcnt(3)" ::: "memory");
    else if (c == 1)
      asm volatile("s_waitcnt vmcnt(4)" ::: "memory");
    else if (c == CPG - 1)
      asm volatile("s_waitcnt vmcnt(2)" ::: "memory");
    else
      asm volatile("s_waitcnt vmcnt(5)" ::: "memory");
    __builtin_amdgcn_sched_barrier(0);   // rule #18: no hoisting past the wait

    // Prefetch 2 channels ahead into the slot freed at iter c-1.
    if (c + 2 < CPG) LOAD(c + 2, s2i);

    const f32x4 zz = {0.f, 0.f, 0.f, 0.f};
    f32x4 f0 = hasUp ? q[s][0] : zz;     // row h-1 (zero at image top)
    f32x4 f1 = q[s][1];                  // row h
    f32x4 f2 = hasDn ? q[s][2] : zz;     // row h+1 (zero at image bottom)

    // w-halos via wave shuffles (wave spans the full row; lane edges = image edges)
    float l0 = __shfl_up(f0.w, 1),  l1 = __shfl_up(f1.w, 1),  l2 = __shfl_up(f2.w, 1);
    float r0 = __shfl_down(f0.x, 1), r1 = __shfl_down(f1.x, 1), r2 = __shfl_down(f2.x, 1);
    if (tx == 0)  { l0 = 0.f; l1 = 0.f; l2 = 0.f; }
    if (tx == 63) { r0 = 0.f; r1 = 0.f; r2 = 0.f; }

    f32x4 acc = f1;                      // residual: out = feat + FAC
    acc.x += l0   * a[0].x + f0.x * a[1].x + f0.y * a[2].x;
    acc.y += f0.x * a[0].y + f0.y * a[1].y + f0.z * a[2].y;
    acc.z += f0.y * a[0].z + f0.z * a[1].z + f0.w * a[2].z;
    acc.w += f0.z * a[0].w + f0.w * a[1].w + r0   * a[2].w;

    acc.x += l1   * a[3].x + f1.x * a[4].x + f1.y * a[5].x;
    acc.y += f1.x * a[3].y + f1.y * a[4].y + f1.z * a[5].y;
    acc.z += f1.y * a[3].z + f1.z * a[4].z + f1.w * a[5].z;
    acc.w += f1.z * a[3].w + f1.w * a[4].w + r1   * a[5].w;

    acc.x += l2   * a[6].x + f2.x * a[7].x + f2.y * a[8].x;
    acc.y += f2.x * a[6].y + f2.y * a[7].y + f2.z * a[8].y;
    acc.z += f2.y * a[6].z + f2.z * a[7].z + f2.w * a[8].z;
    acc.w += f2.z * a[6].w + f2.w * a[7].w + r2   * a[8].w;

    // Output is never re-read: nontemporal store keeps L2/L3 for the inputs.
    __builtin_nontemporal_store(acc, (f32x4*)(obase + (size_t)c * plane));
  }
}

extern "C" void kernel_launch(void* const* d_in, const int* in_sizes, int n_in,
                              void* d_out, int out_size, void* d_ws, size_t ws_size,
                              hipStream_t stream) {
  const float* feat = (const float*)d_in[0];
  const float* att  = (const float*)d_in[1];
  float* out        = (float*)d_out;
  fac_kernel<<<NWG, 256, 0, stream>>>(feat, att, out);
}